// Round 1
// baseline (290.370 us; speedup 1.0000x reference)
//
#include <hip/hip_runtime.h>

// WaveNet-ish: 10 stacked causal dilated conv1d (1ch, k=2, dil=2^i), then 1x1 -> 256ch.
// B=16, T=16384, final length 15361, classes 256.

#define NL     10
#define B_     16
#define T_     16384
#define SHRINK 1023          // sum_{i<10} 2^i
#define LFIN   15361         // T_ - SHRINK
#define NC     256
#define TO     1024          // outputs per tile
#define TILES  16            // ceil(LFIN / TO)
#define NIN_MAX 2047         // TO + SHRINK

// ---------------- kernel 1: compute final hidden h[B][LFIN] into workspace ----------------
__global__ __launch_bounds__(256) void wn_compute_h(
    const float* __restrict__ x,      // [B][T]
    const float* __restrict__ cw,     // [NL][2]
    const float* __restrict__ cb,     // [NL]
    float* __restrict__ h)            // [B][LFIN]
{
    __shared__ float lds[2048];
    const int blk  = blockIdx.x;
    const int b    = blk >> 4;        // / TILES
    const int tile = blk & 15;
    const int s0   = tile * TO;
    int n_in = T_ - s0; if (n_in > NIN_MAX) n_in = NIN_MAX;
    const int tid = threadIdx.x;

    #pragma unroll
    for (int j = 0; j < 8; ++j) {
        int idx = tid + j * 256;
        if (idx < n_in) lds[idx] = x[b * T_ + s0 + idx];
    }
    __syncthreads();

    int cur = n_in;
    #pragma unroll
    for (int i = 0; i < NL; ++i) {
        const int d   = 1 << i;
        const int len = cur - d;
        const float w0 = cw[2 * i], w1 = cw[2 * i + 1], bb = cb[i];
        float vals[8];
        #pragma unroll
        for (int j = 0; j < 8; ++j) {
            int t = tid + j * 256;
            if (t < len) {
                float v = fmaf(w0, lds[t], fmaf(w1, lds[t + d], bb));
                vals[j] = v > 0.f ? v : 0.f;
            }
        }
        __syncthreads();
        #pragma unroll
        for (int j = 0; j < 8; ++j) {
            int t = tid + j * 256;
            if (t < len) lds[t] = vals[j];
        }
        __syncthreads();
        cur = len;
    }

    int n_out = LFIN - s0; if (n_out > TO) n_out = TO;
    #pragma unroll
    for (int j = 0; j < 4; ++j) {
        int t = tid + j * 256;
        if (t < n_out) h[b * LFIN + s0 + t] = lds[t];
    }
}

// ---------------- kernel 2: out[b][c][t] = ow[c]*h[b][t] + ob[c], float4 streaming ----------------
__global__ __launch_bounds__(256) void wn_broadcast(
    const float* __restrict__ h,      // [B][LFIN]
    const float* __restrict__ ow,     // [NC]
    const float* __restrict__ ob,     // [NC]
    float4* __restrict__ out)         // [B][NC][LFIN] / 4
{
    const unsigned total4 = (unsigned)(((size_t)B_ * NC * LFIN) / 4);  // 15,729,664
    unsigned i = blockIdx.x * 256u + threadIdx.x;
    const unsigned stride = gridDim.x * 256u;
    for (; i < total4; i += stride) {
        unsigned idx = i * 4u;
        unsigned row = idx / (unsigned)LFIN;       // b*NC + c   (magic-mul by compiler)
        unsigned t   = idx - row * (unsigned)LFIN;
        float res[4];
        unsigned r = row, tt = t;
        #pragma unroll
        for (int k = 0; k < 4; ++k) {
            unsigned bb = r >> 8;                  // / NC
            unsigned cc = r & (NC - 1);
            res[k] = fmaf(ow[cc], h[bb * LFIN + tt], ob[cc]);
            ++tt;
            if (tt == (unsigned)LFIN) { tt = 0; ++r; }
        }
        out[i] = make_float4(res[0], res[1], res[2], res[3]);
    }
}

// ---------------- fallback: fused (only if ws too small; should not trigger) ----------------
__global__ __launch_bounds__(256) void wn_fused(
    const float* __restrict__ x, const float* __restrict__ cw, const float* __restrict__ cb,
    const float* __restrict__ ow, const float* __restrict__ ob, float* __restrict__ out)
{
    __shared__ float lds[2048];
    const int blk  = blockIdx.x;
    const int b    = blk >> 4;
    const int tile = blk & 15;
    const int s0   = tile * TO;
    int n_in = T_ - s0; if (n_in > NIN_MAX) n_in = NIN_MAX;
    const int tid = threadIdx.x;

    #pragma unroll
    for (int j = 0; j < 8; ++j) {
        int idx = tid + j * 256;
        if (idx < n_in) lds[idx] = x[b * T_ + s0 + idx];
    }
    __syncthreads();

    int cur = n_in;
    #pragma unroll
    for (int i = 0; i < NL; ++i) {
        const int d = 1 << i;
        const int len = cur - d;
        const float w0 = cw[2 * i], w1 = cw[2 * i + 1], bb = cb[i];
        float vals[8];
        #pragma unroll
        for (int j = 0; j < 8; ++j) {
            int t = tid + j * 256;
            if (t < len) {
                float v = fmaf(w0, lds[t], fmaf(w1, lds[t + d], bb));
                vals[j] = v > 0.f ? v : 0.f;
            }
        }
        __syncthreads();
        #pragma unroll
        for (int j = 0; j < 8; ++j) {
            int t = tid + j * 256;
            if (t < len) lds[t] = vals[j];
        }
        __syncthreads();
        cur = len;
    }

    int n_out = LFIN - s0; if (n_out > TO) n_out = TO;
    for (int c = 0; c < NC; ++c) {
        const float w = ow[c], bb2 = ob[c];
        size_t base = ((size_t)b * NC + c) * LFIN + s0;
        for (int t = tid; t < n_out; t += 256) {
            out[base + t] = fmaf(w, lds[t], bb2);
        }
    }
}

extern "C" void kernel_launch(void* const* d_in, const int* in_sizes, int n_in,
                              void* d_out, int out_size, void* d_ws, size_t ws_size,
                              hipStream_t stream) {
    const float* x  = (const float*)d_in[0];
    const float* cw = (const float*)d_in[1];
    const float* cb = (const float*)d_in[2];
    const float* ow = (const float*)d_in[3];
    const float* ob = (const float*)d_in[4];
    float* out = (float*)d_out;

    const size_t need = (size_t)B_ * LFIN * sizeof(float);   // ~983 KB
    if (ws_size >= need) {
        float* h = (float*)d_ws;
        wn_compute_h<<<B_ * TILES, 256, 0, stream>>>(x, cw, cb, h);
        wn_broadcast<<<2048, 256, 0, stream>>>(h, ow, ob, (float4*)out);
    } else {
        wn_fused<<<B_ * TILES, 256, 0, stream>>>(x, cw, cb, ow, ob, out);
    }
}

// Round 2
// 264.861 us; speedup vs baseline: 1.0963x; 1.0963x over previous
//
#include <hip/hip_runtime.h>

// WaveNet-ish: 10 stacked causal dilated conv1d (1ch, k=2, dil=2^i), then 1x1 -> 256ch.
// B=16, T=16384, receptive shrink 1023, final length 15361, classes 256.
//
// Single fused kernel. Block = (b, t-tile of 1024, group of 32 channels).
// Each block recomputes the h tile in LDS (cheap, 8x redundant) and streams
// 32 channel-rows of aligned float4 stores. Write volume = out size exactly.

#define NL     10
#define B_     16
#define T_     16384
#define SHRINK 1023          // sum_{i<10} 2^i
#define LFIN   15361         // T_ - SHRINK
#define NC     256
#define TO     1024          // h outputs per tile
#define TILES  16            // ceil(LFIN / TO); last tile has 1 output
#define CG     8             // channel-groups per (b,tile)
#define CPW    32            // channels per group  (CG*CPW == NC)

__global__ __launch_bounds__(256) void wn_fused_v2(
    const float* __restrict__ x,      // [B][T]
    const float* __restrict__ cw,     // [NL][2]
    const float* __restrict__ cb,     // [NL]
    const float* __restrict__ ow,     // [NC]
    const float* __restrict__ ob,     // [NC]
    float* __restrict__ out)          // [B][NC][LFIN]
{
    __shared__ float lds[2048];
    const int bid  = blockIdx.x;
    const int cg   = bid & (CG - 1);
    const int tile = (bid >> 3) & (TILES - 1);
    const int b    = bid >> 7;
    const int s0   = tile * TO;
    const int tid  = threadIdx.x;

    int n_in = T_ - s0; if (n_in > TO + SHRINK) n_in = TO + SHRINK;

    // ---- stage x tile into LDS (coalesced) ----
    #pragma unroll
    for (int j = 0; j < 8; ++j) {
        int idx = tid + j * 256;
        if (idx < n_in) lds[idx] = x[b * T_ + s0 + idx];
    }
    __syncthreads();

    // ---- 10 dilated conv layers in LDS ----
    int cur = n_in;
    #pragma unroll
    for (int i = 0; i < NL; ++i) {
        const int d   = 1 << i;
        const int len = cur - d;
        const float w0 = cw[2 * i], w1 = cw[2 * i + 1], bbv = cb[i];
        float vals[8];
        #pragma unroll
        for (int j = 0; j < 8; ++j) {
            int t = tid + j * 256;
            if (t < len) {
                float v = fmaf(w0, lds[t], fmaf(w1, lds[t + d], bbv));
                vals[j] = v > 0.f ? v : 0.f;
            }
        }
        __syncthreads();
        #pragma unroll
        for (int j = 0; j < 8; ++j) {
            int t = tid + j * 256;
            if (t < len) lds[t] = vals[j];
        }
        __syncthreads();
        cur = len;
    }

    int n_out = LFIN - s0; if (n_out > TO) n_out = TO;

    // ---- hoist this thread's 8 h values (covers all 4 alignment windows) ----
    // hv[j] = lds[4*tid + j]; safe: 4*255+4 .. +7 = 1027 < 2048.
    float4 hva = *reinterpret_cast<const float4*>(&lds[4 * tid]);
    float4 hvb = *reinterpret_cast<const float4*>(&lds[4 * tid + 4]);
    float hv[8] = {hva.x, hva.y, hva.z, hva.w, hvb.x, hvb.y, hvb.z, hvb.w};

    // ---- stream 32 channel-rows; alignment offset is compile-time per cc ----
    // row = b*NC + c0 + cc; (b*NC + c0) % 4 == 0, so row % 4 == cc % 4.
    // Row start element = row*LFIN + s0, LFIN % 4 == 1, s0 % 4 == 0
    //   -> start % 4 == (row*1) % 4 == cc % 4 -> head length al0 = (4 - cc%4) % 4.
    const int c0 = cg * CPW;
    const size_t row0 = (size_t)(b * NC + c0);
    #pragma unroll
    for (int cc = 0; cc < CPW; ++cc) {
        const int al0 = (4 - (cc & 3)) & 3;           // compile-time
        int al = al0 > n_out ? n_out : al0;
        const int c = c0 + cc;
        const float w = ow[c], bs = ob[c];            // uniform -> scalar loads
        const size_t base = (row0 + cc) * LFIN + s0;  // element index

        // head (0..3 scalar elements to reach 16B alignment)
        if (tid < al) out[base + tid] = fmaf(w, lds[tid], bs);

        // aligned float4 middle
        const int nv = (n_out - al) >> 2;             // <= 256
        if (tid < nv) {
            const int t = al0 + 4 * tid;              // == al + 4*tid when nv>0
            float4 v = make_float4(fmaf(w, hv[al0 + 0], bs),
                                   fmaf(w, hv[al0 + 1], bs),
                                   fmaf(w, hv[al0 + 2], bs),
                                   fmaf(w, hv[al0 + 3], bs));
            *reinterpret_cast<float4*>(&out[base + t]) = v;
        }

        // tail (0..3 scalar elements)
        const int rem = (n_out - al) & 3;
        const int tstart = al + 4 * nv;
        if (tid < rem) out[base + tstart + tid] = fmaf(w, lds[tstart + tid], bs);
    }
}

extern "C" void kernel_launch(void* const* d_in, const int* in_sizes, int n_in,
                              void* d_out, int out_size, void* d_ws, size_t ws_size,
                              hipStream_t stream) {
    const float* x  = (const float*)d_in[0];
    const float* cw = (const float*)d_in[1];
    const float* cb = (const float*)d_in[2];
    const float* ow = (const float*)d_in[3];
    const float* ob = (const float*)d_in[4];
    float* out = (float*)d_out;
    (void)d_ws; (void)ws_size; (void)in_sizes; (void)n_in; (void)out_size;

    wn_fused_v2<<<B_ * TILES * CG, 256, 0, stream>>>(x, cw, cb, ow, ob, out);
}